// Round 3
// baseline (1451.997 us; speedup 1.0000x reference)
//
#include <hip/hip_runtime.h>
#include <stdint.h>

// ---------------------------------------------------------------------------
// DecoderRNN: 3-layer GRU (B=256, T=512, IN=64, H=128) + FC(128->6)
// R3: fuse L0+L1 scans (pipelined with 1-step skew; gx1 computed in-MFMA,
//     gemm gx1 deleted). Phases: [gemm gx0][fused01][gemm gx2][scan L2+FC]
// ---------------------------------------------------------------------------

#define B_   256
#define T_   512
#define IN_  64
#define H_   128
#define G_   384   // 3*H

typedef short bf16x8 __attribute__((ext_vector_type(8)));
typedef float f32x4  __attribute__((ext_vector_type(4)));
typedef unsigned long long u64x2 __attribute__((ext_vector_type(2)));

__device__ __forceinline__ unsigned short f2bf(float f) {
  union { float f; unsigned u; } v; v.f = f;
  unsigned u = v.u;
  u += 0x7fffu + ((u >> 16) & 1u);   // RNE
  return (unsigned short)(u >> 16);
}
__device__ __forceinline__ float bf2f(unsigned short h) {
  union { unsigned u; float f; } v; v.u = ((unsigned)h) << 16; return v.f;
}

__device__ __forceinline__ void gload16(const void* g, void* l) {
  __builtin_amdgcn_global_load_lds(
      (const __attribute__((address_space(1))) void*)g,
      (__attribute__((address_space(3))) void*)l, 16, 0, 0);
}

// load one [gate-col]x[K] B-fragment row set (K=128) as 4 bf16x8 frags
__device__ __forceinline__ void load_bfrag(const float* W, int gcol, int g4,
                                           bf16x8* dst) {
#pragma unroll
  for (int ks = 0; ks < 4; ++ks) {
    const float* p = W + (size_t)gcol * H_ + ks * 32 + g4 * 8;
    float4 v0 = *(const float4*)p;
    float4 v1 = *(const float4*)(p + 4);
    bf16x8 f;
    f[0] = (short)f2bf(v0.x); f[1] = (short)f2bf(v0.y);
    f[2] = (short)f2bf(v0.z); f[3] = (short)f2bf(v0.w);
    f[4] = (short)f2bf(v1.x); f[5] = (short)f2bf(v1.y);
    f[6] = (short)f2bf(v1.z); f[7] = (short)f2bf(v1.w);
    dst[ks] = f;
  }
}

// ---------------------------------------------------------------------------
// GEMM: gx[(t*256+b)*384 + g] = sum_k A[m][k] * W[g][k]   (bf16 MFMA, f32 acc)
// (unchanged from R2)
// ---------------------------------------------------------------------------
template <int K, bool AF32>
__global__ __launch_bounds__(512) void gemm_gx(const void* __restrict__ Ap,
                                               const float* __restrict__ W,
                                               unsigned short* __restrict__ gx) {
  __shared__ __align__(16) unsigned short smem[(128 + G_) * K];
  unsigned short* lA = smem;
  unsigned short* lW = smem + 128 * K;
  const int tid = threadIdx.x;
  const int m0 = blockIdx.x * 128;

  if (AF32) {
    const float* A = (const float*)Ap;
    const int nch = 128 * K / 4;
    for (int c = tid; c < nch; c += 512) {
      int row = c / (K / 4), kq = c - row * (K / 4);
      float4 v = *(const float4*)(A + (size_t)(m0 + row) * K + kq * 4);
      unsigned long long pk = (unsigned long long)f2bf(v.x) |
                              ((unsigned long long)f2bf(v.y) << 16) |
                              ((unsigned long long)f2bf(v.z) << 32) |
                              ((unsigned long long)f2bf(v.w) << 48);
      unsigned byte = ((unsigned)(row * K + kq * 4) * 2u) ^ (((unsigned)row & 7u) << 4);
      *(unsigned long long*)((char*)lA + byte) = pk;
    }
  } else {
    const unsigned short* A = (const unsigned short*)Ap;
    const int nch = 128 * K / 8;
    for (int c = tid; c < nch; c += 512) {
      int row = c / (K / 8), ko = c - row * (K / 8);
      bf16x8 v = *(const bf16x8*)(A + (size_t)(m0 + row) * K + ko * 8);
      unsigned byte = ((unsigned)(row * K + ko * 8) * 2u) ^ (((unsigned)row & 7u) << 4);
      *(bf16x8*)((char*)lA + byte) = v;
    }
  }
  {
    const int nch = G_ * K / 4;
    for (int c = tid; c < nch; c += 512) {
      int g = c / (K / 4), kq = c - g * (K / 4);
      float4 v = *(const float4*)(W + (size_t)g * K + kq * 4);
      unsigned long long pk = (unsigned long long)f2bf(v.x) |
                              ((unsigned long long)f2bf(v.y) << 16) |
                              ((unsigned long long)f2bf(v.z) << 32) |
                              ((unsigned long long)f2bf(v.w) << 48);
      unsigned byte = ((unsigned)(g * K + kq * 4) * 2u) ^ (((unsigned)g & 7u) << 4);
      *(unsigned long long*)((char*)lW + byte) = pk;
    }
  }
  __syncthreads();

  const int l = tid & 63, w = tid >> 6;
  const int rg = w >> 2, cg = w & 3;
  const int lr = l & 15, g4 = l >> 4;

  f32x4 acc[4][6];
#pragma unroll
  for (int i = 0; i < 4; ++i)
#pragma unroll
    for (int j = 0; j < 6; ++j) acc[i][j] = (f32x4){0.f, 0.f, 0.f, 0.f};

#pragma unroll
  for (int ks = 0; ks < K / 32; ++ks) {
    bf16x8 a[4];
#pragma unroll
    for (int i = 0; i < 4; ++i) {
      int row = (rg * 4 + i) * 16 + lr;
      unsigned byte = ((unsigned)(row * K + ks * 32 + g4 * 8) * 2u) ^ (((unsigned)row & 7u) << 4);
      a[i] = *(const bf16x8*)((const char*)lA + byte);
    }
#pragma unroll
    for (int j = 0; j < 6; ++j) {
      int g = (cg * 6 + j) * 16 + lr;
      unsigned byte = ((unsigned)(g * K + ks * 32 + g4 * 8) * 2u) ^ (((unsigned)g & 7u) << 4);
      bf16x8 bfr = *(const bf16x8*)((const char*)lW + byte);
#pragma unroll
      for (int i = 0; i < 4; ++i)
        acc[i][j] = __builtin_amdgcn_mfma_f32_16x16x32_bf16(a[i], bfr, acc[i][j], 0, 0, 0);
    }
  }

  unsigned short* lC = smem;
#pragma unroll
  for (int half = 0; half < 2; ++half) {
    __syncthreads();
    if (rg == half) {
#pragma unroll
      for (int i = 0; i < 4; ++i)
#pragma unroll
        for (int j = 0; j < 6; ++j)
#pragma unroll
          for (int r = 0; r < 4; ++r) {
            int mloc = i * 16 + g4 * 4 + r;
            int g = (cg * 6 + j) * 16 + lr;
            lC[mloc * 388 + g] = f2bf(acc[i][j][r]);
          }
    }
    __syncthreads();
    for (int it = 0; it < 6; ++it) {
      int c = tid + it * 512;
      int mloc = c / 48, cb = c - mloc * 48;
      unsigned long long lo =
          *(const unsigned long long*)((const char*)lC + mloc * 776 + cb * 16);
      unsigned long long hi =
          *(const unsigned long long*)((const char*)lC + mloc * 776 + cb * 16 + 8);
      int m = m0 + half * 64 + mloc;
      int row;
      if (AF32) { int t = m & 511, b = m >> 9; row = t * 256 + b; }
      else      { row = m; }
      u64x2 v; v[0] = lo; v[1] = hi;
      *(u64x2*)((char*)gx + (size_t)row * (G_ * 2) + cb * 16) = v;
    }
  }
}

// ---------------------------------------------------------------------------
// Fused L0+L1 scan. 64 blocks x 4 batch rows, 512 threads (8 waves).
// Iteration i (0..512): L0 computes step i (if i<512), L1 computes step i-1
// (if i>0). Two independent dep chains per iteration fill each other's stalls.
// gx1 is NOT materialized: L1's r/z accumulate h0*w_ih1 + h1*w_hh1 in one
// 8-deep MFMA chain; n keeps input/recurrent parts in separate accs.
// Weight frags (36 = 144 VGPR) live in registers all 513 iterations.
// ---------------------------------------------------------------------------
__global__ __launch_bounds__(512) void gru_fused01(
    const unsigned short* __restrict__ gx0,  // [T][256][384] bf16
    const float* __restrict__ Whh0,          // [384][128]
    const float* __restrict__ Wih1,          // [384][128]
    const float* __restrict__ Whh1,          // [384][128]
    const float* __restrict__ bih,           // [3][384] (layers 0,1 used)
    const float* __restrict__ bhh,           // [3][384]
    unsigned short* __restrict__ h1seq) {    // [T][256][128] bf16
  __shared__ __align__(16) unsigned short lh0[2][512];   // [4][128] bf16, swz
  __shared__ __align__(16) unsigned short lh1[2][512];
  __shared__ __align__(16) unsigned short lgx[4][1536];  // ring 4x[4][384] bf16
  __shared__ __align__(16) float bounce[8][7 * 64];      // 7 gate-tiles/wave

  const int tid = threadIdx.x, l = tid & 63, w = tid >> 6;
  const int lr = l & 15, g4 = l >> 4;
  const int b0 = blockIdx.x * 4;
  const int batch = g4;                 // 0..3
  const int hcol = w * 16 + lr;         // 0..127

  for (int i = tid; i < 2048; i += 512) {
    ((unsigned short*)lh0)[i & 1023] = 0;   // both buffers of lh0 (1024 u16)
    ((unsigned short*)lh1)[i & 1023] = 0;
  }

  // biases
  const float c0_r  = bih[hcol]       + bhh[hcol];
  const float c0_z  = bih[128 + hcol] + bhh[128 + hcol];
  const float c0_n1 = bih[256 + hcol];
  const float c0_n2 = bhh[256 + hcol];
  const float c1_r  = bih[G_ + hcol]       + bhh[G_ + hcol];
  const float c1_z  = bih[G_ + 128 + hcol] + bhh[G_ + 128 + hcol];
  const float c1_n1 = bih[G_ + 256 + hcol];
  const float c1_n2 = bhh[G_ + 256 + hcol];

  // weight fragments: 3 matrices x 3 gates x 4 k-chunks = 36 frags (144 VGPR)
  bf16x8 W0[3][4], Wi[3][4], Wh[3][4];
#pragma unroll
  for (int ci = 0; ci < 3; ++ci) {
    int gcol = (w + ci * 8) * 16 + lr;
    load_bfrag(Whh0, gcol, g4, W0[ci]);
    load_bfrag(Wih1, gcol, g4, Wi[ci]);
    load_bfrag(Whh1, gcol, g4, Wh[ci]);
  }

  // drain, then prime gx0 ring (tiles t=0,1,2 by waves 0..2)
  __syncthreads();
  if (w < 3) {
#pragma unroll
    for (int p = 0; p < 3; ++p) {
      const char* src = (const char*)gx0 + ((size_t)(p * 256 + b0) * G_) * 2 + (size_t)tid * 16;
      gload16(src, (char*)&lgx[p][0] + w * 1024);
    }
    asm volatile("s_waitcnt vmcnt(2)" ::: "memory");
  }
  asm volatile("s_waitcnt lgkmcnt(0)" ::: "memory");
  __builtin_amdgcn_s_barrier();
  __builtin_amdgcn_sched_barrier(0);

  float h0reg = 0.f, h1reg = 0.f;
  float* myb = &bounce[w][0];

  for (int i = 0; i <= T_; ++i) {
    const int cur = i & 1, nxt = cur ^ 1;
    const int slot = i & 3;

    // ---- A fragments (clamped-address full-wave reads from 1KB buffers;
    //      lanes lr>=4 read junk rows -> only garbage D-rows >=4, never used)
    bf16x8 a0[4], a1[4];
#pragma unroll
    for (int ks = 0; ks < 4; ++ks) {
      unsigned byA = ((unsigned)((lr & 3) * 256 + ks * 64 + g4 * 16)) ^ (((unsigned)lr & 3u) << 4);
      a0[ks] = *(const bf16x8*)((const char*)lh0[cur] + byA);
      a1[ks] = *(const bf16x8*)((const char*)lh1[cur] + byA);
    }

    // ---- MFMA: L0 (12) + L1 r/z fused 8-chains (16) + L1 n split (8)
    f32x4 R0 = {0,0,0,0}, Z0 = {0,0,0,0}, N0 = {0,0,0,0};
    f32x4 R1 = {0,0,0,0}, Z1 = {0,0,0,0}, NX1 = {0,0,0,0}, NH1 = {0,0,0,0};
#pragma unroll
    for (int ks = 0; ks < 4; ++ks) {
      R0 = __builtin_amdgcn_mfma_f32_16x16x32_bf16(a0[ks], W0[0][ks], R0, 0, 0, 0);
      Z0 = __builtin_amdgcn_mfma_f32_16x16x32_bf16(a0[ks], W0[1][ks], Z0, 0, 0, 0);
      N0 = __builtin_amdgcn_mfma_f32_16x16x32_bf16(a0[ks], W0[2][ks], N0, 0, 0, 0);
      R1 = __builtin_amdgcn_mfma_f32_16x16x32_bf16(a0[ks], Wi[0][ks], R1, 0, 0, 0);
      Z1 = __builtin_amdgcn_mfma_f32_16x16x32_bf16(a0[ks], Wi[1][ks], Z1, 0, 0, 0);
      NX1 = __builtin_amdgcn_mfma_f32_16x16x32_bf16(a0[ks], Wi[2][ks], NX1, 0, 0, 0);
      R1 = __builtin_amdgcn_mfma_f32_16x16x32_bf16(a1[ks], Wh[0][ks], R1, 0, 0, 0);
      Z1 = __builtin_amdgcn_mfma_f32_16x16x32_bf16(a1[ks], Wh[1][ks], Z1, 0, 0, 0);
      NH1 = __builtin_amdgcn_mfma_f32_16x16x32_bf16(a1[ks], Wh[2][ks], NH1, 0, 0, 0);
    }

    // ---- redistribute via LDS bounce: lanes 0-15 hold D rows 0-3 (f32x4)
    if (l < 16) {
      *(f32x4*)(myb + 0 * 64 + lr * 4) = R0;
      *(f32x4*)(myb + 1 * 64 + lr * 4) = Z0;
      *(f32x4*)(myb + 2 * 64 + lr * 4) = N0;
      *(f32x4*)(myb + 3 * 64 + lr * 4) = R1;
      *(f32x4*)(myb + 4 * 64 + lr * 4) = Z1;
      *(f32x4*)(myb + 5 * 64 + lr * 4) = NX1;
      *(f32x4*)(myb + 6 * 64 + lr * 4) = NH1;
    }
    asm volatile("s_waitcnt lgkmcnt(0)" ::: "memory");
    __builtin_amdgcn_sched_barrier(0);
    const float hWr0 = myb[0 * 64 + lr * 4 + g4];
    const float hWz0 = myb[1 * 64 + lr * 4 + g4];
    const float hWn0 = myb[2 * 64 + lr * 4 + g4];
    const float sR1  = myb[3 * 64 + lr * 4 + g4];
    const float sZ1  = myb[4 * 64 + lr * 4 + g4];
    const float sNX1 = myb[5 * 64 + lr * 4 + g4];
    const float sNH1 = myb[6 * 64 + lr * 4 + g4];

    // ---- L0 gates (step i)
    if (i < T_) {
      const float gxr = bf2f(lgx[slot][batch * G_ + hcol]);
      const float gxz = bf2f(lgx[slot][batch * G_ + 128 + hcol]);
      const float gxn = bf2f(lgx[slot][batch * G_ + 256 + hcol]);
      const float rg = 1.f / (1.f + __expf(-(gxr + hWr0 + c0_r)));
      const float zg = 1.f / (1.f + __expf(-(gxz + hWz0 + c0_z)));
      const float nx = gxn + c0_n1 + rg * (hWn0 + c0_n2);
      const float ng = 1.f - 2.f / (__expf(2.f * nx) + 1.f);
      h0reg = (1.f - zg) * ng + zg * h0reg;
      *(unsigned short*)((char*)lh0[nxt] +
          (((unsigned)(batch * 256 + hcol * 2)) ^ ((unsigned)batch << 4))) = f2bf(h0reg);
    }

    // ---- L1 gates (step i-1)
    if (i > 0) {
      const float rg = 1.f / (1.f + __expf(-(sR1 + c1_r)));
      const float zg = 1.f / (1.f + __expf(-(sZ1 + c1_z)));
      const float nx = sNX1 + c1_n1 + rg * (sNH1 + c1_n2);
      const float ng = 1.f - 2.f / (__expf(2.f * nx) + 1.f);
      h1reg = (1.f - zg) * ng + zg * h1reg;
      const unsigned short hb = f2bf(h1reg);
      *(unsigned short*)((char*)lh1[nxt] +
          (((unsigned)(batch * 256 + hcol * 2)) ^ ((unsigned)batch << 4))) = hb;
      h1seq[(size_t)((i - 1) * 256 + b0 + batch) * H_ + hcol] = hb;
    }

    // ---- ring load for tile i+3 (clamped; uniform issue count every iter)
    if (w < 3) {
      int t3 = i + 3; if (t3 > T_ - 1) t3 = T_ - 1;
      const char* src = (const char*)gx0 + ((size_t)(t3 * 256 + b0) * G_) * 2 + (size_t)tid * 16;
      gload16(src, (char*)&lgx[(i + 3) & 3][0] + w * 1024);
    }

    __builtin_amdgcn_sched_barrier(0);
    if (w < 3) {
      // steady (i>=1): pre-wait outstanding = [.., L(i+1), S(i-2), L(i+2), S(i-1), L(i+3)]
      //   vmcnt(3) retires through L(i+1).   i==0: [L1,L2,L3] -> vmcnt(2).
      if (i == 0) asm volatile("s_waitcnt vmcnt(2)" ::: "memory");
      else        asm volatile("s_waitcnt vmcnt(3)" ::: "memory");
    }
    asm volatile("s_waitcnt lgkmcnt(0)" ::: "memory");
    __builtin_amdgcn_s_barrier();
    __builtin_amdgcn_sched_barrier(0);
  }
}

// ---------------------------------------------------------------------------
// GRU scan (single layer) -- unchanged from R2; used for L2 (+FC).
// ---------------------------------------------------------------------------
template <int DOSEQ, int DOFC>
__global__ __launch_bounds__(512) void gru_scan(
    const unsigned short* __restrict__ gx,
    const float* __restrict__ Whh,
    const float* __restrict__ bih,
    const float* __restrict__ bhh,
    unsigned short* __restrict__ hseq,
    const float* __restrict__ fcw,
    const float* __restrict__ fcb,
    float* __restrict__ out) {
  __shared__ __align__(16) unsigned short lh[2][2048];
  __shared__ __align__(16) unsigned short lgx[4][1536];

  const int tid = threadIdx.x, l = tid & 63, w = tid >> 6;
  const int lr = l & 15, g4 = l >> 4;
  const int b0 = blockIdx.x * 4;
  const int batch = g4;
  const int hcol = w * 16 + lr;

  for (int i = tid; i < 4096; i += 512) ((unsigned short*)lh)[i] = 0;

  const float c_r  = bih[hcol]           + bhh[hcol];
  const float c_z  = bih[128 + hcol]     + bhh[128 + hcol];
  const float c_n1 = bih[256 + hcol];
  const float c_n2 = bhh[256 + hcol];

  bf16x8 Bf[3][4];
#pragma unroll
  for (int ci = 0; ci < 3; ++ci)
    load_bfrag(Whh, (w + ci * 8) * 16 + lr, g4, Bf[ci]);

  __syncthreads();
  if (w < 3) {
#pragma unroll
    for (int p = 0; p < 3; ++p) {
      const char* src = (const char*)gx + ((size_t)(p * 256 + b0) * G_) * 2 + (size_t)tid * 16;
      gload16(src, (char*)&lgx[p][0] + w * 1024);
    }
    asm volatile("s_waitcnt vmcnt(2)" ::: "memory");
  }
  asm volatile("s_waitcnt lgkmcnt(0)" ::: "memory");
  __builtin_amdgcn_s_barrier();
  __builtin_amdgcn_sched_barrier(0);

  float hreg = 0.f;

  for (int t = 0; t < T_; ++t) {
    const int cur = t & 1, nxt = cur ^ 1;
    const int slot = t & 3;

    bf16x8 a[4];
#pragma unroll
    for (int ks = 0; ks < 4; ++ks) {
      unsigned byte = ((unsigned)(lr * 256 + ks * 64 + g4 * 16)) ^ (((unsigned)lr & 7u) << 4);
      a[ks] = *(const bf16x8*)((const char*)lh[cur] + byte);
    }
    const float gxr = bf2f(lgx[slot][batch * G_ + hcol]);
    const float gxz = bf2f(lgx[slot][batch * G_ + 128 + hcol]);
    const float gxn = bf2f(lgx[slot][batch * G_ + 256 + hcol]);

    f32x4 aR = {0,0,0,0}, aZ = {0,0,0,0}, aN = {0,0,0,0};
#pragma unroll
    for (int ks = 0; ks < 4; ++ks) {
      aR = __builtin_amdgcn_mfma_f32_16x16x32_bf16(a[ks], Bf[0][ks], aR, 0, 0, 0);
      aZ = __builtin_amdgcn_mfma_f32_16x16x32_bf16(a[ks], Bf[1][ks], aZ, 0, 0, 0);
      aN = __builtin_amdgcn_mfma_f32_16x16x32_bf16(a[ks], Bf[2][ks], aN, 0, 0, 0);
    }

    float hWr, hWz, hWn;
    {
      float y0 = __shfl(aR[0], lr, 64), y1 = __shfl(aR[1], lr, 64);
      float y2 = __shfl(aR[2], lr, 64), y3 = __shfl(aR[3], lr, 64);
      hWr = batch == 0 ? y0 : batch == 1 ? y1 : batch == 2 ? y2 : y3;
    }
    {
      float y0 = __shfl(aZ[0], lr, 64), y1 = __shfl(aZ[1], lr, 64);
      float y2 = __shfl(aZ[2], lr, 64), y3 = __shfl(aZ[3], lr, 64);
      hWz = batch == 0 ? y0 : batch == 1 ? y1 : batch == 2 ? y2 : y3;
    }
    {
      float y0 = __shfl(aN[0], lr, 64), y1 = __shfl(aN[1], lr, 64);
      float y2 = __shfl(aN[2], lr, 64), y3 = __shfl(aN[3], lr, 64);
      hWn = batch == 0 ? y0 : batch == 1 ? y1 : batch == 2 ? y2 : y3;
    }

    const float rg = 1.f / (1.f + __expf(-(gxr + hWr + c_r)));
    const float zg = 1.f / (1.f + __expf(-(gxz + hWz + c_z)));
    const float nx = gxn + c_n1 + rg * (hWn + c_n2);
    const float ng = 1.f - 2.f / (__expf(2.f * nx) + 1.f);
    hreg = (1.f - zg) * ng + zg * hreg;

    const unsigned short hb = f2bf(hreg);
    *(unsigned short*)((char*)lh[nxt] +
        (((unsigned)(batch * 256 + hcol * 2)) ^ ((unsigned)batch << 4))) = hb;
    if (DOSEQ)
      hseq[(size_t)(t * 256 + b0 + batch) * H_ + hcol] = hb;

    if (w < 3) {
      int t3 = t + 3; if (t3 > T_ - 1) t3 = T_ - 1;
      const char* src = (const char*)gx + ((size_t)(t3 * 256 + b0) * G_) * 2 + (size_t)tid * 16;
      gload16(src, (char*)&lgx[(t + 3) & 3][0] + w * 1024);
    }

    __builtin_amdgcn_sched_barrier(0);
    if (w < 3) {
      asm volatile("s_waitcnt vmcnt(%0)" :: "n"(DOSEQ ? 3 : 2) : "memory");
    }
    asm volatile("s_waitcnt lgkmcnt(0)" ::: "memory");
    __builtin_amdgcn_s_barrier();
    __builtin_amdgcn_sched_barrier(0);
  }

  if (DOFC) {
    __syncthreads();
    float* sc = (float*)&lgx[0][0];
    sc[batch * H_ + hcol] = hreg;
    __syncthreads();
    if (tid < 24) {
      int b = tid / 6, c = tid - b * 6;
      float s = fcb[c];
      for (int k = 0; k < H_; ++k) s += sc[b * H_ + k] * fcw[c * H_ + k];
      out[(size_t)(b0 + b) * 6 + c] = s;
    }
  }
}

// ---------------------------------------------------------------------------
extern "C" void kernel_launch(void* const* d_in, const int* in_sizes, int n_in,
                              void* d_out, int out_size, void* d_ws, size_t ws_size,
                              hipStream_t stream) {
  const float* x     = (const float*)d_in[0];
  const float* w_ih0 = (const float*)d_in[1];
  const float* w_ih1 = (const float*)d_in[2];
  const float* w_ih2 = (const float*)d_in[3];
  const float* w_hh  = (const float*)d_in[4];
  const float* b_ih  = (const float*)d_in[5];
  const float* b_hh  = (const float*)d_in[6];
  const float* fc_w  = (const float*)d_in[7];
  const float* fc_b  = (const float*)d_in[8];
  float* out = (float*)d_out;

  unsigned short* gxb  = (unsigned short*)d_ws;          // 96 MB
  unsigned short* hseq = gxb + (size_t)T_ * B_ * G_;     // 32 MB

  // layer 0 input projection
  gemm_gx<64, true><<<1024, 512, 0, stream>>>((const void*)x, w_ih0, gxb);
  // fused layers 0+1 scan (h1seq out; gx1 never materialized)
  gru_fused01<<<64, 512, 0, stream>>>(gxb, w_hh, w_ih1, w_hh + 1 * G_ * H_,
                                      b_ih, b_hh, hseq);
  // layer 2
  gemm_gx<128, false><<<1024, 512, 0, stream>>>((const void*)hseq, w_ih2, gxb);
  gru_scan<0, 1><<<64, 512, 0, stream>>>(gxb, w_hh + 2 * G_ * H_, b_ih + 2 * G_,
                                         b_hh + 2 * G_, nullptr, fc_w, fc_b, out);
}

// Round 5
// 1305.701 us; speedup vs baseline: 1.1120x; 1.1120x over previous
//
#include <hip/hip_runtime.h>
#include <stdint.h>

// ---------------------------------------------------------------------------
// DecoderRNN: 3-layer GRU (B=256, T=512, IN=64, H=128) + FC(128->6)
// R4 (resubmit; R4 bench was an infra timeout): 3 separate scans.
// Scan LDS diet: clamped-broadcast A-reads from compact [4][128] h buffer,
// LDS bounce (not shfl/bpermute) for D redistribution, compact lh writes.
// GEMM unchanged from R2.
// ---------------------------------------------------------------------------

#define B_   256
#define T_   512
#define IN_  64
#define H_   128
#define G_   384   // 3*H

typedef short bf16x8 __attribute__((ext_vector_type(8)));
typedef float f32x4  __attribute__((ext_vector_type(4)));
typedef unsigned long long u64x2 __attribute__((ext_vector_type(2)));

__device__ __forceinline__ unsigned short f2bf(float f) {
  union { float f; unsigned u; } v; v.f = f;
  unsigned u = v.u;
  u += 0x7fffu + ((u >> 16) & 1u);   // RNE
  return (unsigned short)(u >> 16);
}
__device__ __forceinline__ float bf2f(unsigned short h) {
  union { unsigned u; float f; } v; v.u = ((unsigned)h) << 16; return v.f;
}

__device__ __forceinline__ void gload16(const void* g, void* l) {
  __builtin_amdgcn_global_load_lds(
      (const __attribute__((address_space(1))) void*)g,
      (__attribute__((address_space(3))) void*)l, 16, 0, 0);
}

// load one [gate-col]x[128] B-fragment row as 4 bf16x8 frags (from f32 W)
__device__ __forceinline__ void load_bfrag(const float* W, int gcol, int g4,
                                           bf16x8* dst) {
#pragma unroll
  for (int ks = 0; ks < 4; ++ks) {
    const float* p = W + (size_t)gcol * H_ + ks * 32 + g4 * 8;
    float4 v0 = *(const float4*)p;
    float4 v1 = *(const float4*)(p + 4);
    bf16x8 f;
    f[0] = (short)f2bf(v0.x); f[1] = (short)f2bf(v0.y);
    f[2] = (short)f2bf(v0.z); f[3] = (short)f2bf(v0.w);
    f[4] = (short)f2bf(v1.x); f[5] = (short)f2bf(v1.y);
    f[6] = (short)f2bf(v1.z); f[7] = (short)f2bf(v1.w);
    dst[ks] = f;
  }
}

// ---------------------------------------------------------------------------
// GEMM: gx[(t*256+b)*384 + g] = sum_k A[m][k] * W[g][k]  (unchanged from R2)
// ---------------------------------------------------------------------------
template <int K, bool AF32>
__global__ __launch_bounds__(512) void gemm_gx(const void* __restrict__ Ap,
                                               const float* __restrict__ W,
                                               unsigned short* __restrict__ gx) {
  __shared__ __align__(16) unsigned short smem[(128 + G_) * K];
  unsigned short* lA = smem;
  unsigned short* lW = smem + 128 * K;
  const int tid = threadIdx.x;
  const int m0 = blockIdx.x * 128;

  if (AF32) {
    const float* A = (const float*)Ap;
    const int nch = 128 * K / 4;
    for (int c = tid; c < nch; c += 512) {
      int row = c / (K / 4), kq = c - row * (K / 4);
      float4 v = *(const float4*)(A + (size_t)(m0 + row) * K + kq * 4);
      unsigned long long pk = (unsigned long long)f2bf(v.x) |
                              ((unsigned long long)f2bf(v.y) << 16) |
                              ((unsigned long long)f2bf(v.z) << 32) |
                              ((unsigned long long)f2bf(v.w) << 48);
      unsigned byte = ((unsigned)(row * K + kq * 4) * 2u) ^ (((unsigned)row & 7u) << 4);
      *(unsigned long long*)((char*)lA + byte) = pk;
    }
  } else {
    const unsigned short* A = (const unsigned short*)Ap;
    const int nch = 128 * K / 8;
    for (int c = tid; c < nch; c += 512) {
      int row = c / (K / 8), ko = c - row * (K / 8);
      bf16x8 v = *(const bf16x8*)(A + (size_t)(m0 + row) * K + ko * 8);
      unsigned byte = ((unsigned)(row * K + ko * 8) * 2u) ^ (((unsigned)row & 7u) << 4);
      *(bf16x8*)((char*)lA + byte) = v;
    }
  }
  {
    const int nch = G_ * K / 4;
    for (int c = tid; c < nch; c += 512) {
      int g = c / (K / 4), kq = c - g * (K / 4);
      float4 v = *(const float4*)(W + (size_t)g * K + kq * 4);
      unsigned long long pk = (unsigned long long)f2bf(v.x) |
                              ((unsigned long long)f2bf(v.y) << 16) |
                              ((unsigned long long)f2bf(v.z) << 32) |
                              ((unsigned long long)f2bf(v.w) << 48);
      unsigned byte = ((unsigned)(g * K + kq * 4) * 2u) ^ (((unsigned)g & 7u) << 4);
      *(unsigned long long*)((char*)lW + byte) = pk;
    }
  }
  __syncthreads();

  const int l = tid & 63, w = tid >> 6;
  const int rg = w >> 2, cg = w & 3;
  const int lr = l & 15, g4 = l >> 4;

  f32x4 acc[4][6];
#pragma unroll
  for (int i = 0; i < 4; ++i)
#pragma unroll
    for (int j = 0; j < 6; ++j) acc[i][j] = (f32x4){0.f, 0.f, 0.f, 0.f};

#pragma unroll
  for (int ks = 0; ks < K / 32; ++ks) {
    bf16x8 a[4];
#pragma unroll
    for (int i = 0; i < 4; ++i) {
      int row = (rg * 4 + i) * 16 + lr;
      unsigned byte = ((unsigned)(row * K + ks * 32 + g4 * 8) * 2u) ^ (((unsigned)row & 7u) << 4);
      a[i] = *(const bf16x8*)((const char*)lA + byte);
    }
#pragma unroll
    for (int j = 0; j < 6; ++j) {
      int g = (cg * 6 + j) * 16 + lr;
      unsigned byte = ((unsigned)(g * K + ks * 32 + g4 * 8) * 2u) ^ (((unsigned)g & 7u) << 4);
      bf16x8 bfr = *(const bf16x8*)((const char*)lW + byte);
#pragma unroll
      for (int i = 0; i < 4; ++i)
        acc[i][j] = __builtin_amdgcn_mfma_f32_16x16x32_bf16(a[i], bfr, acc[i][j], 0, 0, 0);
    }
  }

  unsigned short* lC = smem;
#pragma unroll
  for (int half = 0; half < 2; ++half) {
    __syncthreads();
    if (rg == half) {
#pragma unroll
      for (int i = 0; i < 4; ++i)
#pragma unroll
        for (int j = 0; j < 6; ++j)
#pragma unroll
          for (int r = 0; r < 4; ++r) {
            int mloc = i * 16 + g4 * 4 + r;
            int g = (cg * 6 + j) * 16 + lr;
            lC[mloc * 388 + g] = f2bf(acc[i][j][r]);
          }
    }
    __syncthreads();
    for (int it = 0; it < 6; ++it) {
      int c = tid + it * 512;
      int mloc = c / 48, cb = c - mloc * 48;
      unsigned long long lo =
          *(const unsigned long long*)((const char*)lC + mloc * 776 + cb * 16);
      unsigned long long hi =
          *(const unsigned long long*)((const char*)lC + mloc * 776 + cb * 16 + 8);
      int m = m0 + half * 64 + mloc;
      int row;
      if (AF32) { int t = m & 511, b = m >> 9; row = t * 256 + b; }
      else      { row = m; }
      u64x2 v; v[0] = lo; v[1] = hi;
      *(u64x2*)((char*)gx + (size_t)row * (G_ * 2) + cb * 16) = v;
    }
  }
}

// ---------------------------------------------------------------------------
// GRU scan: 64 blocks x 4 batch rows, 512 threads (8 waves).
// LDS-diet version:
//  - h lives in compact [4][128] bf16 double-buffer (XOR ^(row<<4) swizzle);
//    A-frags read with CLAMPED addresses (lanes lr>=4 broadcast lr&3's lines:
//    256B unique/instr instead of 1KB; D rows 4-15 are duplicates, unread).
//  - D redistribution via per-wave LDS bounce (3x b128 write by lanes 0-15,
//    lgkmcnt(0), 3x b32 read) -- replaces 12 ds_bpermute + selects.
//  - gx ring via global_load_lds + counted vmcnt (unchanged from R2).
// ---------------------------------------------------------------------------
template <int DOSEQ, int DOFC>
__global__ __launch_bounds__(512) void gru_scan(
    const unsigned short* __restrict__ gx,   // [T][256][384] bf16
    const float* __restrict__ Whh,           // [384][128]
    const float* __restrict__ bih,           // [384]
    const float* __restrict__ bhh,           // [384]
    unsigned short* __restrict__ hseq,       // [T][256][128] bf16 (if DOSEQ)
    const float* __restrict__ fcw,           // [6][128] (if DOFC)
    const float* __restrict__ fcb,           // [6]
    float* __restrict__ out) {               // [256][6]
  __shared__ __align__(16) unsigned short lh[2][512];    // [4][128] bf16, swz
  __shared__ __align__(16) unsigned short lgx[4][1536];  // ring 4x[4][384] bf16
  __shared__ __align__(16) float bounce[8][3][16][4];    // per-wave D exchange

  const int tid = threadIdx.x, l = tid & 63, w = tid >> 6;
  const int lr = l & 15, g4 = l >> 4;
  const int b0 = blockIdx.x * 4;
  const int hcol = w * 16 + lr;         // 0..127

  // zero both h buffers (1024 u16)
  for (int i = tid; i < 1024; i += 512) ((unsigned short*)lh)[i] = 0;

  const float c_r  = bih[hcol]           + bhh[hcol];
  const float c_z  = bih[128 + hcol]     + bhh[128 + hcol];
  const float c_n1 = bih[256 + hcol];
  const float c_n2 = bhh[256 + hcol];

  // W_hh fragments in registers (12 frags = 48 VGPR); gcol = gate*128 + hcol
  bf16x8 Bf[3][4];
#pragma unroll
  for (int ci = 0; ci < 3; ++ci)
    load_bfrag(Whh, ci * 128 + hcol, g4, Bf[ci]);

  // full drain (so in-loop vmcnt counts only ring loads + hseq stores)
  __syncthreads();
  if (w < 3) {
#pragma unroll
    for (int p = 0; p < 3; ++p) {
      const char* src = (const char*)gx + ((size_t)(p * 256 + b0) * G_) * 2 + (size_t)tid * 16;
      gload16(src, (char*)&lgx[p][0] + w * 1024);
    }
    asm volatile("s_waitcnt vmcnt(2)" ::: "memory");
  }
  asm volatile("s_waitcnt lgkmcnt(0)" ::: "memory");
  __builtin_amdgcn_s_barrier();
  __builtin_amdgcn_sched_barrier(0);

  float hreg = 0.f;

  for (int t = 0; t < T_; ++t) {
    const int cur = t & 1, nxt = cur ^ 1;
    const int slot = t & 3;

    // gx gate inputs (issued early; consumed after MFMA)
    const float gxr = bf2f(lgx[slot][g4 * G_ + hcol]);
    const float gxz = bf2f(lgx[slot][g4 * G_ + 128 + hcol]);
    const float gxn = bf2f(lgx[slot][g4 * G_ + 256 + hcol]);

    // clamped-broadcast A-frags: row = lr&3 (16 unique 16B lines per instr)
    bf16x8 a[4];
#pragma unroll
    for (int ks = 0; ks < 4; ++ks) {
      unsigned row = (unsigned)lr & 3u;
      unsigned byte = (row * 256u + (unsigned)ks * 64u + (unsigned)g4 * 16u) ^ (row << 4);
      a[ks] = *(const bf16x8*)((const char*)lh[cur] + byte);
    }

    f32x4 aR = {0.f,0.f,0.f,0.f}, aZ = {0.f,0.f,0.f,0.f}, aN = {0.f,0.f,0.f,0.f};
#pragma unroll
    for (int ks = 0; ks < 4; ++ks) {
      aR = __builtin_amdgcn_mfma_f32_16x16x32_bf16(a[ks], Bf[0][ks], aR, 0, 0, 0);
      aZ = __builtin_amdgcn_mfma_f32_16x16x32_bf16(a[ks], Bf[1][ks], aZ, 0, 0, 0);
      aN = __builtin_amdgcn_mfma_f32_16x16x32_bf16(a[ks], Bf[2][ks], aN, 0, 0, 0);
    }

    // bounce: lanes 0-15 hold D rows 0-3 (batches) for col=lr
    if (l < 16) {
      *(f32x4*)&bounce[w][0][lr][0] = aR;
      *(f32x4*)&bounce[w][1][lr][0] = aZ;
      *(f32x4*)&bounce[w][2][lr][0] = aN;
    }
    asm volatile("s_waitcnt lgkmcnt(0)" ::: "memory");
    __builtin_amdgcn_sched_barrier(0);
    const float hWr = bounce[w][0][lr][g4];
    const float hWz = bounce[w][1][lr][g4];
    const float hWn = bounce[w][2][lr][g4];

    const float rg = 1.f / (1.f + __expf(-(gxr + hWr + c_r)));
    const float zg = 1.f / (1.f + __expf(-(gxz + hWz + c_z)));
    const float nx = gxn + c_n1 + rg * (hWn + c_n2);
    const float ng = 1.f - 2.f / (__expf(2.f * nx) + 1.f);
    hreg = (1.f - zg) * ng + zg * hreg;   // carry path stays fp32

    const unsigned short hb = f2bf(hreg);
    *(unsigned short*)((char*)lh[nxt] +
        (((unsigned)(g4 * 256 + hcol * 2)) ^ (((unsigned)g4) << 4))) = hb;
    if (DOSEQ)
      hseq[(size_t)(t * 256 + b0 + g4) * H_ + hcol] = hb;

    // ring load t+3 (clamped index; uniform issue count every iter)
    if (w < 3) {
      int t3 = t + 3; if (t3 > T_ - 1) t3 = T_ - 1;
      const char* src = (const char*)gx + ((size_t)(t3 * 256 + b0) * G_) * 2 + (size_t)tid * 16;
      gload16(src, (char*)&lgx[(t + 3) & 3][0] + w * 1024);
    }

    __builtin_amdgcn_sched_barrier(0);
    if (w < 3) {
      // DOSEQ steady queue: [L(t+1), S(t-1), L(t+2), S(t), L(t+3)] -> vmcnt(3)
      // DOFC : [L(t+1), L(t+2), L(t+3)] -> vmcnt(2)
      asm volatile("s_waitcnt vmcnt(%0)" :: "n"(DOSEQ ? 3 : 2) : "memory");
    }
    asm volatile("s_waitcnt lgkmcnt(0)" ::: "memory");
    __builtin_amdgcn_s_barrier();
    __builtin_amdgcn_sched_barrier(0);
  }

  if (DOFC) {
    __syncthreads();
    float* sc = (float*)&lgx[0][0];
    sc[g4 * H_ + hcol] = hreg;
    __syncthreads();
    if (tid < 24) {
      int b = tid / 6, c = tid - b * 6;
      float s = fcb[c];
      for (int k = 0; k < H_; ++k) s += sc[b * H_ + k] * fcw[c * H_ + k];
      out[(size_t)(b0 + b) * 6 + c] = s;
    }
  }
}

// ---------------------------------------------------------------------------
extern "C" void kernel_launch(void* const* d_in, const int* in_sizes, int n_in,
                              void* d_out, int out_size, void* d_ws, size_t ws_size,
                              hipStream_t stream) {
  const float* x     = (const float*)d_in[0];  // [256][512][64]
  const float* w_ih0 = (const float*)d_in[1];  // [384][64]
  const float* w_ih1 = (const float*)d_in[2];  // [384][128]
  const float* w_ih2 = (const float*)d_in[3];  // [384][128]
  const float* w_hh  = (const float*)d_in[4];  // [3][384][128]
  const float* b_ih  = (const float*)d_in[5];  // [3][384]
  const float* b_hh  = (const float*)d_in[6];  // [3][384]
  const float* fc_w  = (const float*)d_in[7];  // [6][128]
  const float* fc_b  = (const float*)d_in[8];  // [6]
  float* out = (float*)d_out;                  // [256][6]

  unsigned short* gxb  = (unsigned short*)d_ws;          // 96 MB
  unsigned short* hseq = gxb + (size_t)T_ * B_ * G_;     // 32 MB

  // layer 0
  gemm_gx<64, true><<<1024, 512, 0, stream>>>((const void*)x, w_ih0, gxb);
  gru_scan<1, 0><<<64, 512, 0, stream>>>(gxb, w_hh, b_ih, b_hh, hseq,
                                         nullptr, nullptr, nullptr);
  // layer 1
  gemm_gx<128, false><<<1024, 512, 0, stream>>>((const void*)hseq, w_ih1, gxb);
  gru_scan<1, 0><<<64, 512, 0, stream>>>(gxb, w_hh + 1 * G_ * H_, b_ih + G_,
                                         b_hh + G_, hseq, nullptr, nullptr, nullptr);
  // layer 2 (+FC fused)
  gemm_gx<128, false><<<1024, 512, 0, stream>>>((const void*)hseq, w_ih2, gxb);
  gru_scan<0, 1><<<64, 512, 0, stream>>>(gxb, w_hh + 2 * G_ * H_, b_ih + 2 * G_,
                                         b_hh + 2 * G_, nullptr, fc_w, fc_b, out);
}